// Round 5
// baseline (29.991 us; speedup 1.0000x reference)
//
#include <hip/hip_runtime.h>
#include <math.h>

// BrownianKernelLayer: K[i,j] = 0.5 * sum_d (|x_id|^p + |X2_jd|^p - |x_id - X2_jd|^p)
// p = 2 * softplus(log_H), H = p/2.  N=M=2048, D=16, fp32 in/out.
//
// v5: one transcendental per term, zero LDS in the hot path.
//   s = u^2 = m * 2^(b-127);  (float)bits * 2^-23 = b + (m-1)
//   log2(s) = bits_f*2^-23 + (log2(m) - (m-1)) - 127
//   s^H = exp2( H*2^-23 * bits_f + Q(m) ),  Q(m) = H*(log2 m - (m-1)) - 127H
// Q is a degree-4 runtime Chebyshev fit (err ~5e-4 on log2 -> rel ~3e-4).
// Per term: sub, mul, cvt_f32_u32, and_or, 5 fma, v_exp, add
//   = 10 full-rate VALU + 1 trans  (vs 3 VALU + 2 trans in v2 = 52 cyc/term).
// u=0 -> bits=0 -> m=1, arg = -127H ~ -108 -> exp2 ~ 0 (correct, no epsilon).

#define D_DIM 16
#define BLK 64

__device__ __forceinline__ float log2f_hw(float v) {
    return __builtin_amdgcn_logf(v);   // v_log_f32 (log2)
}

__global__ __launch_bounds__(256) void fbm_kernel(
    const float* __restrict__ x,    // [N, 16]
    const float* __restrict__ X2,   // [M, 16]
    const float* __restrict__ logH, // [1]
    float* __restrict__ out,        // [N, M]
    int N, int M)
{
    __shared__ float xs[D_DIM][BLK];   // transposed x tile
    __shared__ float ys[D_DIM][BLK];   // transposed X2 tile
    __shared__ float t1s[BLK];
    __shared__ float t2s[BLK];

    const int tid  = threadIdx.x;
    const int brow = blockIdx.y * BLK;
    const int bcol = blockIdx.x * BLK;

    const float H = log1pf(expf(logH[0]));  // softplus(log_H)

    // ---- fit deg-4 poly for phi(m) = log2(m) - (m-1) on [1,2], Cheb nodes
    const float T1 = 0.475528258f, T2 = 0.293892626f;
    float m0 = 1.5f + T1, m1 = 1.5f + T2, m2 = 1.5f, m3 = 1.5f - T2, m4 = 1.5f - T1;
    float f0 = log2f_hw(m0) - (m0 - 1.0f);
    float f1 = log2f_hw(m1) - (m1 - 1.0f);
    float f2 = log2f_hw(m2) - (m2 - 1.0f);
    float f3 = log2f_hw(m3) - (m3 - 1.0f);
    float f4 = log2f_hw(m4) - (m4 - 1.0f);
    float s1 = 0.5f * (f0 + f4), d1 = 0.5f * (f0 - f4);
    float s2 = 0.5f * (f1 + f3), d2 = 0.5f * (f1 - f3);
    float u1 = T1 * T1, u2 = T2 * T2;
    float A = s1 - f2, B = s2 - f2;
    float det = u1 * u2 * (u2 - u1);
    float e1 = (A * u2 * u2 - B * u1 * u1) / det;
    float e2 = (B * u1 - A * u2) / det;
    float Ap = d1 / T1, Bp = d2 / T2;
    float o1 = (Ap - Bp) / (u1 - u2);
    float o0 = Ap - o1 * u1;
    // shift t = m - 1.5 to monomial in m
    float a4 = e2;
    float a3 = o1 - 6.0f * e2;
    float a2 = e1 - 4.5f * o1 + 13.5f * e2;
    float a1 = o0 - 3.0f * e1 + 6.75f * o1 - 13.5f * e2;
    float a0 = f2 - 1.5f * o0 + 2.25f * e1 - 3.375f * o1 + 5.0625f * e2;
    // scale by H, fold -127H into constant
    const float q4 = H * a4;
    const float q3 = H * a3;
    const float q2 = H * a2;
    const float q1 = H * a1;
    const float q0 = H * a0 - 127.0f * H;
    const float HB = H * (1.0f / 8388608.0f);   // H * 2^-23

    // ---- stage tiles
    {
        float4 vx = ((const float4*)(x  + (size_t)brow * D_DIM))[tid];
        float4 vy = ((const float4*)(X2 + (size_t)bcol * D_DIM))[tid];
        int r  = tid >> 2;
        int d0 = (tid & 3) << 2;
        xs[d0 + 0][r] = vx.x; xs[d0 + 1][r] = vx.y;
        xs[d0 + 2][r] = vx.z; xs[d0 + 3][r] = vx.w;
        ys[d0 + 0][r] = vy.x; ys[d0 + 1][r] = vy.y;
        ys[d0 + 2][r] = vy.z; ys[d0 + 3][r] = vy.w;
    }
    __syncthreads();

    #define POWTERM(S_, DST_) { \
        unsigned bits_ = __float_as_uint(S_); \
        float bf_ = (float)bits_; \
        float mm_ = __uint_as_float((bits_ & 0x007FFFFFu) | 0x3F800000u); \
        float qq_ = fmaf(fmaf(fmaf(fmaf(q4, mm_, q3), mm_, q2), mm_, q1), mm_, q0); \
        float arg_ = fmaf(bf_, HB, qq_); \
        DST_ += __builtin_amdgcn_exp2f(arg_); }

    // ---- per-row self terms t1 (x rows) / t2 (X2 rows)
    if (tid < 128) {
        int r = tid & 63;
        const float (*src)[BLK] = (tid < 64) ? xs : ys;
        float s = 0.0f;
        #pragma unroll
        for (int d = 0; d < D_DIM; ++d) {
            float v = src[d][r];
            float sq = v * v;
            POWTERM(sq, s)
        }
        if (tid < 64) t1s[r] = s; else t2s[r] = s;
    }
    __syncthreads();

    // ---- main: 4x4 outputs per thread; 16x16 thread grid covers 64x64
    const int ti = tid >> 4;
    const int tj = tid & 15;

    float acc[4][4] = {};

    #define TERM(A_, B_, R_, C_) { \
        float u_ = (A_) - (B_); \
        float s_ = u_ * u_; \
        POWTERM(s_, acc[R_][C_]) }

    #pragma unroll
    for (int d = 0; d < D_DIM; ++d) {
        float4 xa = *(const float4*)&xs[d][ti * 4];
        float4 xb = *(const float4*)&ys[d][tj * 4];
        float A0 = xa.x, A1 = xa.y, A2 = xa.z, A3 = xa.w;
        float B0 = xb.x, B1 = xb.y, B2 = xb.z, B3 = xb.w;

        TERM(A0, B0, 0, 0) TERM(A0, B1, 0, 1) TERM(A0, B2, 0, 2) TERM(A0, B3, 0, 3)
        TERM(A1, B0, 1, 0) TERM(A1, B1, 1, 1) TERM(A1, B2, 1, 2) TERM(A1, B3, 1, 3)
        TERM(A2, B0, 2, 0) TERM(A2, B1, 2, 1) TERM(A2, B2, 2, 2) TERM(A2, B3, 2, 3)
        TERM(A3, B0, 3, 0) TERM(A3, B1, 3, 1) TERM(A3, B2, 3, 2) TERM(A3, B3, 3, 3)
    }
    #undef TERM
    #undef POWTERM

    // ---- epilogue: K = 0.5*(t1[i] + t2[j] - t3)
    float t2v0 = t2s[tj * 4 + 0];
    float t2v1 = t2s[tj * 4 + 1];
    float t2v2 = t2s[tj * 4 + 2];
    float t2v3 = t2s[tj * 4 + 3];

    #pragma unroll
    for (int a = 0; a < 4; ++a) {
        float t1v = t1s[ti * 4 + a];
        float4 o;
        o.x = 0.5f * (t1v + t2v0 - acc[a][0]);
        o.y = 0.5f * (t1v + t2v1 - acc[a][1]);
        o.z = 0.5f * (t1v + t2v2 - acc[a][2]);
        o.w = 0.5f * (t1v + t2v3 - acc[a][3]);
        int gi = brow + ti * 4 + a;
        *(float4*)(out + (size_t)gi * M + bcol + tj * 4) = o;
    }
}

extern "C" void kernel_launch(void* const* d_in, const int* in_sizes, int n_in,
                              void* d_out, int out_size, void* d_ws, size_t ws_size,
                              hipStream_t stream) {
    const float* x    = (const float*)d_in[0];
    const float* X2   = (const float*)d_in[1];
    const float* logH = (const float*)d_in[2];
    float* out = (float*)d_out;

    int N = in_sizes[0] / D_DIM;
    int M = in_sizes[1] / D_DIM;

    dim3 grid(M / BLK, N / BLK);
    dim3 block(256);
    fbm_kernel<<<grid, block, 0, stream>>>(x, X2, logH, out, N, M);
}

// Round 6
// 22.206 us; speedup vs baseline: 1.3506x; 1.3506x over previous
//
#include <hip/hip_runtime.h>
#include <math.h>

// BrownianKernelLayer: K[i,j] = 0.5 * sum_d (|x_id|^p + |X2_jd|^p - |x_id - X2_jd|^p)
// p = 2 * softplus(log_H).  N=M=2048, D=16, fp32 in/out.
//
// v6 = v2 math (minimal 5-instr term: sub, log|.|, mul, exp, add) with 2x
// occupancy: 64x32 tile, 4x2 micro-tile, 2048 blocks = 8 blocks/CU = 8
// waves/SIMD (hardware max). Low register pressure on purpose: 8 accs,
// d-loop unrolled only 4x, so VGPR stays <= 64 and all 8 blocks reside.

#define D_DIM 16
#define BR 64   // rows per tile (x)
#define BC 32   // cols per tile (X2)

__device__ __forceinline__ float powp(float t, float p) {
    // t >= 0; t^p = exp2(p*log2(t)); log2(0) = -inf -> exp2 -> 0 (correct)
    return __builtin_amdgcn_exp2f(p * __builtin_amdgcn_logf(t));
}

__global__ __launch_bounds__(256) void fbm_kernel(
    const float* __restrict__ x,    // [N, 16]
    const float* __restrict__ X2,   // [M, 16]
    const float* __restrict__ logH, // [1]
    float* __restrict__ out,        // [N, M]
    int N, int M)
{
    __shared__ float xs[D_DIM][BR];   // transposed x tile
    __shared__ float ys[D_DIM][BC];   // transposed X2 tile
    __shared__ float t1s[BR];
    __shared__ float t2s[BC];

    const int tid  = threadIdx.x;
    const int brow = blockIdx.y * BR;
    const int bcol = blockIdx.x * BC;

    const float p = 2.0f * log1pf(expf(logH[0]));  // 2*softplus

    // ---- stage x tile: 64 rows x 16 d = 1024 floats = 256 x float4
    {
        float4 vx = ((const float4*)(x + (size_t)brow * D_DIM))[tid];
        int r  = tid >> 2;
        int d0 = (tid & 3) << 2;
        xs[d0 + 0][r] = vx.x; xs[d0 + 1][r] = vx.y;
        xs[d0 + 2][r] = vx.z; xs[d0 + 3][r] = vx.w;
    }
    // ---- stage X2 tile: 32 rows x 16 d = 512 floats = 128 x float4
    if (tid < 128) {
        float4 vy = ((const float4*)(X2 + (size_t)bcol * D_DIM))[tid];
        int r  = tid >> 2;
        int d0 = (tid & 3) << 2;
        ys[d0 + 0][r] = vy.x; ys[d0 + 1][r] = vy.y;
        ys[d0 + 2][r] = vy.z; ys[d0 + 3][r] = vy.w;
    }
    __syncthreads();

    // ---- per-row self terms
    if (tid < BR) {
        float s = 0.0f;
        #pragma unroll
        for (int d = 0; d < D_DIM; ++d) s += powp(fabsf(xs[d][tid]), p);
        t1s[tid] = s;
    } else if (tid < BR + BC) {
        int r = tid - BR;
        float s = 0.0f;
        #pragma unroll
        for (int d = 0; d < D_DIM; ++d) s += powp(fabsf(ys[d][r]), p);
        t2s[r] = s;
    }
    __syncthreads();

    // ---- main: 4x2 outputs per thread; 16x16 thread grid covers 64x32
    const int ti = tid >> 4;   // row group (4 rows)
    const int tj = tid & 15;   // col group (2 cols)

    float acc[4][2] = {};

    #pragma unroll 4
    for (int d = 0; d < D_DIM; ++d) {
        float4 xa = *(const float4*)&xs[d][ti * 4];
        float2 xb = *(const float2*)&ys[d][tj * 2];
        float A0 = xa.x, A1 = xa.y, A2 = xa.z, A3 = xa.w;
        float B0 = xb.x, B1 = xb.y;

        acc[0][0] += powp(fabsf(A0 - B0), p);
        acc[0][1] += powp(fabsf(A0 - B1), p);
        acc[1][0] += powp(fabsf(A1 - B0), p);
        acc[1][1] += powp(fabsf(A1 - B1), p);
        acc[2][0] += powp(fabsf(A2 - B0), p);
        acc[2][1] += powp(fabsf(A2 - B1), p);
        acc[3][0] += powp(fabsf(A3 - B0), p);
        acc[3][1] += powp(fabsf(A3 - B1), p);
    }

    // ---- epilogue: K = 0.5*(t1[i] + t2[j] - t3)
    float t2v0 = t2s[tj * 2 + 0];
    float t2v1 = t2s[tj * 2 + 1];

    #pragma unroll
    for (int a = 0; a < 4; ++a) {
        float t1v = t1s[ti * 4 + a];
        float2 o;
        o.x = 0.5f * (t1v + t2v0 - acc[a][0]);
        o.y = 0.5f * (t1v + t2v1 - acc[a][1]);
        int gi = brow + ti * 4 + a;
        *(float2*)(out + (size_t)gi * M + bcol + tj * 2) = o;
    }
}

extern "C" void kernel_launch(void* const* d_in, const int* in_sizes, int n_in,
                              void* d_out, int out_size, void* d_ws, size_t ws_size,
                              hipStream_t stream) {
    const float* x    = (const float*)d_in[0];
    const float* X2   = (const float*)d_in[1];
    const float* logH = (const float*)d_in[2];
    float* out = (float*)d_out;

    int N = in_sizes[0] / D_DIM;
    int M = in_sizes[1] / D_DIM;

    dim3 grid(M / BC, N / BR);
    dim3 block(256);
    fbm_kernel<<<grid, block, 0, stream>>>(x, X2, logH, out, N, M);
}